// Round 1
// baseline (400.627 us; speedup 1.0000x reference)
//
#include <hip/hip_runtime.h>
#include <math.h>

#define C_N 50000
#define D_N 1024

// ---- ws layout (float offsets, all multiples of 16) ----
#define OQ     0        // Q[1024]
#define OSB    1024     // sbias[16]
#define OM     1040     // max[16]
#define OS     1056     // sum[16]
#define OP     2048     // P[16][1024] pooled nodes (unnormalized)
#define OZ     18432    // z[2048]
#define OH     20480    // hbuf[1024]
#define OY     21504    // ybuf[1024]
#define OMAXP  22528    // max partials 196*16
#define OSUMP  26624    // sum partials 196*16
#define OWQP   30720    // Wq partials 8*1024
#define OWVP   38912    // Wv partials 8*1024
#define OW1P   47104    // W1 partials 16*1024
#define OW2P   63488    // W2 partials 8*1024
#define OQK    71680    // qk[1024][16]
#define OSC    88064    // scores/weights [C][16] (in-place exp)
#define OPP    888064   // pool partials nb*16384

__device__ __forceinline__ int brev4(int l){
  return ((l&1)<<3)|((l&2)<<1)|((l&4)>>1)|((l&8)>>3);
}

// Sum v[0..15] over all 64 lanes. Every lane returns the total for
// head h = brev4(lane&15).
__device__ __forceinline__ float treduce16_add(float v[16], int lane){
#pragma unroll
  for (int k=0;k<8;k++){
    float send = (lane&1)? v[k] : v[k+8];
    float got  = __shfl_xor(send,1);
    v[k] = ((lane&1)? v[k+8] : v[k]) + got;
  }
#pragma unroll
  for (int k=0;k<4;k++){
    float send = (lane&2)? v[k] : v[k+4];
    float got  = __shfl_xor(send,2);
    v[k] = ((lane&2)? v[k+4] : v[k]) + got;
  }
#pragma unroll
  for (int k=0;k<2;k++){
    float send = (lane&4)? v[k] : v[k+2];
    float got  = __shfl_xor(send,4);
    v[k] = ((lane&4)? v[k+2] : v[k]) + got;
  }
  {
    float send = (lane&8)? v[0] : v[1];
    float got  = __shfl_xor(send,8);
    v[0] = ((lane&8)? v[1] : v[0]) + got;
  }
  float t = v[0];
  t += __shfl_xor(t,16);
  t += __shfl_xor(t,32);
  return t;
}

__device__ __forceinline__ float treduce16_max(float v[16], int lane){
#pragma unroll
  for (int k=0;k<8;k++){
    float send = (lane&1)? v[k] : v[k+8];
    float got  = __shfl_xor(send,1);
    v[k] = fmaxf(((lane&1)? v[k+8] : v[k]), got);
  }
#pragma unroll
  for (int k=0;k<4;k++){
    float send = (lane&2)? v[k] : v[k+4];
    float got  = __shfl_xor(send,2);
    v[k] = fmaxf(((lane&2)? v[k+4] : v[k]), got);
  }
#pragma unroll
  for (int k=0;k<2;k++){
    float send = (lane&4)? v[k] : v[k+2];
    float got  = __shfl_xor(send,4);
    v[k] = fmaxf(((lane&4)? v[k+2] : v[k]), got);
  }
  {
    float send = (lane&8)? v[0] : v[1];
    float got  = __shfl_xor(send,8);
    v[0] = fmaxf(((lane&8)? v[1] : v[0]), got);
  }
  float t = v[0];
  t = fmaxf(t, __shfl_xor(t,16));
  t = fmaxf(t, __shfl_xor(t,32));
  return t;
}

// Generic column-parallel matvec partial: out_j = sum_i x[i]*W[i*1024+j]
// grid (4, IB), chunk rows per y-block.
__global__ __launch_bounds__(256) void hm_mv_part(const float* __restrict__ W,
    const float* __restrict__ x, float* __restrict__ part, int chunk){
  int j = blockIdx.x*256 + threadIdx.x;
  int i0 = blockIdx.y*chunk;
  float acc = 0.f;
#pragma unroll 4
  for (int i=i0;i<i0+chunk;i++)
    acc = fmaf(x[i], W[(size_t)i*1024 + j], acc);
  part[(size_t)blockIdx.y*1024 + j] = acc;
}

// Q = sum partials + bq ; sbias[h] = sum_d Q[h*64+d]*bk[h*64+d]
__global__ __launch_bounds__(256) void hm_wq_red(const float* __restrict__ part,
    const float* __restrict__ bq, const float* __restrict__ bk,
    float* __restrict__ Q, float* __restrict__ sbias){
  __shared__ float tmp[256];
  int tid = threadIdx.x;
  int j = blockIdx.x*256 + tid;
  float q = bq[j];
#pragma unroll
  for (int ib=0; ib<8; ib++) q += part[ib*1024 + j];
  Q[j] = q;
  tmp[tid] = q * bk[j];
  __syncthreads();
  if (tid < 4){
    float s = 0.f;
    for (int t=0;t<64;t++) s += tmp[tid*64 + t];
    sbias[blockIdx.x*4 + tid] = s;
  }
}

// qk[i][h] = sum_t Wk[i][h*64+t] * Q[h*64+t], one wave per row i.
__global__ __launch_bounds__(256) void hm_qk(const float* __restrict__ Wk,
    const float* __restrict__ Q, float* __restrict__ qk){
  __shared__ float qlds[1024];
  int tid = threadIdx.x;
  for (int k=tid;k<1024;k+=256) qlds[k]=Q[k];
  __syncthreads();
  int w = tid>>6, l = tid&63;
  int i = blockIdx.x*4 + w;
  float acc[16];
#pragma unroll
  for (int k=0;k<16;k++)
    acc[k] = Wk[(size_t)i*1024 + k*64 + l] * qlds[k*64 + l];
  float t = treduce16_add(acc, l);
  if (l < 16) qk[i*16 + brev4(l)] = t;
}

// scores[c][h] = (nodes[c]·qk[:,h] + sbias[h]) / 8
// Block = 4 waves; wave w owns K-quarter, holds its qk slice in 64 VGPRs.
__global__ __launch_bounds__(256) void hm_scores(const float* __restrict__ nodes,
    const float* __restrict__ qk, const float* __restrict__ sbias,
    float* __restrict__ scores){
  __shared__ float part[16][4][16];
  const int tid = threadIdx.x, w = tid>>6, l = tid&63;
  float qr[4][16];
  {
    const float4* q4 = (const float4*)qk;
    int base4 = (w*256 + l*4)*4;
#pragma unroll
    for (int j=0;j<4;j++)
#pragma unroll
      for (int g=0;g<4;g++){
        float4 t = q4[base4 + j*4 + g];
        qr[j][g*4+0]=t.x; qr[j][g*4+1]=t.y; qr[j][g*4+2]=t.z; qr[j][g*4+3]=t.w;
      }
  }
  float sb = sbias[tid&15];
  const float4* n4 = (const float4*)nodes;
  const int nbatch = C_N/16; // 3125 exactly
  for (int cb = blockIdx.x; cb < nbatch; cb += gridDim.x){
#pragma unroll 1
    for (int r=0;r<16;r++){
      int c = cb*16 + r;
      float4 nv = n4[(size_t)c*256 + w*64 + l];
      float nvv[4] = {nv.x, nv.y, nv.z, nv.w};
      float acc[16];
#pragma unroll
      for (int h=0;h<16;h++) acc[h]=0.f;
#pragma unroll
      for (int j=0;j<4;j++){
        float n = nvv[j];
#pragma unroll
        for (int h=0;h<16;h++) acc[h] = fmaf(n, qr[j][h], acc[h]);
      }
      float t = treduce16_add(acc, l);
      if (l < 16) part[r][w][brev4(l)] = t;
    }
    __syncthreads();
    {
      int r = tid>>4, h = tid&15;
      int c = cb*16 + r;
      float s = part[r][0][h]+part[r][1][h]+part[r][2][h]+part[r][3][h];
      scores[(size_t)c*16 + h] = (s + sb) * 0.125f;
    }
    __syncthreads();
  }
}

__global__ __launch_bounds__(256) void hm_max_part(const float* __restrict__ scores,
    float* __restrict__ maxp){
  __shared__ float lds[4][16];
  int tid = threadIdx.x, w = tid>>6, l = tid&63;
  int c = blockIdx.x*256 + tid;
  float v[16];
  if (c < C_N){
    const float4* s4 = (const float4*)(scores + (size_t)c*16);
#pragma unroll
    for (int g=0;g<4;g++){
      float4 t = s4[g];
      v[g*4+0]=t.x; v[g*4+1]=t.y; v[g*4+2]=t.z; v[g*4+3]=t.w;
    }
  } else {
#pragma unroll
    for (int k=0;k<16;k++) v[k] = -3.0e38f;
  }
  float t = treduce16_max(v, l);
  if (l < 16) lds[w][brev4(l)] = t;
  __syncthreads();
  if (tid < 16)
    maxp[blockIdx.x*16 + tid] =
      fmaxf(fmaxf(lds[0][tid],lds[1][tid]), fmaxf(lds[2][tid],lds[3][tid]));
}

__global__ void hm_max_fin(const float* __restrict__ maxp, float* __restrict__ m, int nb){
  int tid = threadIdx.x;
  if (tid < 16){
    float v = -3.0e38f;
    for (int b=0;b<nb;b++) v = fmaxf(v, maxp[b*16 + tid]);
    m[tid] = v;
  }
}

// in-place: scores -> exp(scores - m); also per-block partial sums
__global__ __launch_bounds__(256) void hm_wexp(float* __restrict__ scores,
    const float* __restrict__ m, float* __restrict__ sump){
  __shared__ float lds[4][16];
  int tid = threadIdx.x, w = tid>>6, l = tid&63;
  float mm[16];
  {
    const float4* m4 = (const float4*)m;
#pragma unroll
    for (int g=0;g<4;g++){
      float4 t = m4[g];
      mm[g*4+0]=t.x; mm[g*4+1]=t.y; mm[g*4+2]=t.z; mm[g*4+3]=t.w;
    }
  }
  int c = blockIdx.x*256 + tid;
  float e[16];
#pragma unroll
  for (int k=0;k<16;k++) e[k]=0.f;
  if (c < C_N){
    float4* s4 = (float4*)(scores + (size_t)c*16);
#pragma unroll
    for (int g=0;g<4;g++){
      float4 t = s4[g];
      float e0 = __expf(t.x - mm[g*4+0]);
      float e1 = __expf(t.y - mm[g*4+1]);
      float e2 = __expf(t.z - mm[g*4+2]);
      float e3 = __expf(t.w - mm[g*4+3]);
      s4[g] = make_float4(e0,e1,e2,e3);
      e[g*4+0]=e0; e[g*4+1]=e1; e[g*4+2]=e2; e[g*4+3]=e3;
    }
  }
  float t = treduce16_add(e, l);
  if (l < 16) lds[w][brev4(l)] = t;
  __syncthreads();
  if (tid < 16)
    sump[blockIdx.x*16 + tid] = lds[0][tid]+lds[1][tid]+lds[2][tid]+lds[3][tid];
}

__global__ void hm_sum_fin(const float* __restrict__ sump, float* __restrict__ S, int nb){
  int tid = threadIdx.x;
  if (tid < 16){
    float v = 0.f;
    for (int b=0;b<nb;b++) v += sump[b*16 + tid];
    S[tid] = v;
  }
}

// P[h][i] partials: wave w owns i-quarter; acc[j][h] in registers, no per-row reduce.
__global__ __launch_bounds__(256) void hm_pool(const float* __restrict__ nodes,
    const float* __restrict__ weights, float* __restrict__ parts){
  const int tid = threadIdx.x, w = tid>>6, l = tid&63;
  float acc[4][16];
#pragma unroll
  for (int j=0;j<4;j++)
#pragma unroll
    for (int h=0;h<16;h++) acc[j][h]=0.f;
  const float4* n4 = (const float4*)nodes;
  for (int c = blockIdx.x; c < C_N; c += gridDim.x){
    float4 nv = n4[(size_t)c*256 + w*64 + l];
    float nvv[4] = {nv.x, nv.y, nv.z, nv.w};
    const float4* u4 = (const float4*)(weights + (size_t)c*16);
    float u[16];
#pragma unroll
    for (int g=0;g<4;g++){
      float4 t = u4[g];
      u[g*4+0]=t.x; u[g*4+1]=t.y; u[g*4+2]=t.z; u[g*4+3]=t.w;
    }
#pragma unroll
    for (int j=0;j<4;j++){
      float n = nvv[j];
#pragma unroll
      for (int h=0;h<16;h++) acc[j][h] = fmaf(n, u[h], acc[j][h]);
    }
  }
  float* p = parts + (size_t)blockIdx.x*16384;
#pragma unroll
  for (int h=0;h<16;h++){
    float4 o = make_float4(acc[0][h],acc[1][h],acc[2][h],acc[3][h]);
    ((float4*)p)[(h*1024 + w*256 + l*4)>>2] = o;
  }
}

__global__ __launch_bounds__(256) void hm_pool_red(const float* __restrict__ parts,
    float* __restrict__ P, int nb){
  int j = blockIdx.x*256 + threadIdx.x; // 0..16383
  float s = 0.f;
  for (int b=0;b<nb;b++) s += parts[(size_t)b*16384 + j];
  P[j] = s;
}

// Wv partial: out j uses P row h=j>>6
__global__ __launch_bounds__(256) void hm_wv_part(const float* __restrict__ Wv,
    const float* __restrict__ P, float* __restrict__ part){
  int j = blockIdx.x*256 + threadIdx.x;
  int h = j>>6;
  int i0 = blockIdx.y*128;
  const float* Ph = P + h*1024;
  float acc = 0.f;
#pragma unroll 4
  for (int i=i0;i<i0+128;i++)
    acc = fmaf(Ph[i], Wv[(size_t)i*1024 + j], acc);
  part[(size_t)blockIdx.y*1024 + j] = acc;
}

// z[0:1024] = pooled = sum partials / S[h] + bv ; z[1024:2048] = z_prev
__global__ __launch_bounds__(256) void hm_wv_red(const float* __restrict__ part,
    const float* __restrict__ S, const float* __restrict__ bv,
    const float* __restrict__ z_prev, float* __restrict__ z){
  int b = blockIdx.x, tid = threadIdx.x;
  if (b < 4){
    int j = b*256 + tid;
    int h = j>>6;
    float s = 0.f;
#pragma unroll
    for (int ib=0; ib<8; ib++) s += part[ib*1024 + j];
    z[j] = s / S[h] + bv[j];
  } else {
    int j = (b-4)*256 + tid;
    z[1024 + j] = z_prev[j];
  }
}

__global__ __launch_bounds__(256) void hm_w1_red(const float* __restrict__ part,
    const float* __restrict__ b1, float* __restrict__ hbuf){
  int j = blockIdx.x*256 + threadIdx.x;
  float s = b1[j];
#pragma unroll
  for (int ib=0; ib<16; ib++) s += part[ib*1024 + j];
  // exact GELU: 0.5*x*(1+erf(x/sqrt(2)))
  hbuf[j] = 0.5f * s * (1.0f + erff(s * 0.70710678118654752f));
}

__global__ __launch_bounds__(256) void hm_w2_red(const float* __restrict__ part,
    const float* __restrict__ b2, float* __restrict__ y){
  int j = blockIdx.x*256 + threadIdx.x;
  float s = b2[j];
#pragma unroll
  for (int ib=0; ib<8; ib++) s += part[ib*1024 + j];
  y[j] = s;
}

__global__ __launch_bounds__(256) void hm_rms(const float* __restrict__ y,
    const float* __restrict__ scale, float* __restrict__ out){
  __shared__ float red[4];
  __shared__ float msv;
  int tid = threadIdx.x;
  float local = 0.f;
  for (int j=tid;j<1024;j+=256){ float t = y[j]; local = fmaf(t,t,local); }
#pragma unroll
  for (int m=1;m<64;m<<=1) local += __shfl_xor(local, m);
  if ((tid&63)==0) red[tid>>6] = local;
  __syncthreads();
  if (tid==0){
    float s = red[0]+red[1]+red[2]+red[3];
    msv = rsqrtf(s*(1.0f/1024.0f) + 1e-6f);
  }
  __syncthreads();
  float r = msv;
  for (int j=tid;j<1024;j+=256) out[j] = scale[j]*y[j]*r;
}

extern "C" void kernel_launch(void* const* d_in, const int* in_sizes, int n_in,
                              void* d_out, int out_size, void* d_ws, size_t ws_size,
                              hipStream_t stream){
  const float* nodes  = (const float*)d_in[0];
  const float* z_prev = (const float*)d_in[1];
  const float* Wq = (const float*)d_in[2];
  const float* bq = (const float*)d_in[3];
  const float* Wk = (const float*)d_in[4];
  const float* bk = (const float*)d_in[5];
  const float* Wv = (const float*)d_in[6];
  const float* bv = (const float*)d_in[7];
  const float* W1 = (const float*)d_in[8];
  const float* b1 = (const float*)d_in[9];
  const float* W2 = (const float*)d_in[10];
  const float* b2 = (const float*)d_in[11];
  const float* scale = (const float*)d_in[12];
  float* ws  = (float*)d_ws;
  float* out = (float*)d_out;

  float* Qv   = ws + OQ;
  float* sb   = ws + OSB;
  float* mv   = ws + OM;
  float* Sv   = ws + OS;
  float* P    = ws + OP;
  float* z    = ws + OZ;
  float* hbuf = ws + OH;
  float* ybuf = ws + OY;
  float* maxp = ws + OMAXP;
  float* sump = ws + OSUMP;
  float* wqp  = ws + OWQP;
  float* wvp  = ws + OWVP;
  float* w1p  = ws + OW1P;
  float* w2p  = ws + OW2P;
  float* qk   = ws + OQK;
  float* sc   = ws + OSC;
  float* pp   = ws + OPP;

  size_t wsf = ws_size/4;
  int nbp = 1;
  if (wsf > (size_t)(OPP + 16384)) nbp = (int)((wsf - OPP)/16384);
  if (nbp > 512) nbp = 512;
  if (nbp < 1) nbp = 1;

  const int nmb = (C_N + 255)/256; // 196

  hm_mv_part<<<dim3(4,8),256,0,stream>>>(Wq, z_prev, wqp, 128);
  hm_wq_red<<<4,256,0,stream>>>(wqp, bq, bk, Qv, sb);
  hm_qk<<<256,256,0,stream>>>(Wk, Qv, qk);
  hm_scores<<<512,256,0,stream>>>(nodes, qk, sb, sc);
  hm_max_part<<<nmb,256,0,stream>>>(sc, maxp);
  hm_max_fin<<<1,64,0,stream>>>(maxp, mv, nmb);
  hm_wexp<<<nmb,256,0,stream>>>(sc, mv, sump);
  hm_sum_fin<<<1,64,0,stream>>>(sump, Sv, nmb);
  hm_pool<<<nbp,256,0,stream>>>(nodes, sc, pp);
  hm_pool_red<<<64,256,0,stream>>>(pp, P, nbp);
  hm_wv_part<<<dim3(4,8),256,0,stream>>>(Wv, P, wvp);
  hm_wv_red<<<8,256,0,stream>>>(wvp, Sv, bv, z_prev, z);
  hm_mv_part<<<dim3(4,16),256,0,stream>>>(W1, z, w1p, 128);
  hm_w1_red<<<4,256,0,stream>>>(w1p, b1, hbuf);
  hm_mv_part<<<dim3(4,8),256,0,stream>>>(W2, hbuf, w2p, 128);
  hm_w2_red<<<4,256,0,stream>>>(w2p, b2, ybuf);
  hm_rms<<<1,256,0,stream>>>(ybuf, scale, out);
}

// Round 2
// 320.571 us; speedup vs baseline: 1.2497x; 1.2497x over previous
//
#include <hip/hip_runtime.h>
#include <math.h>

#define C_N 50000

typedef float f32x16 __attribute__((ext_vector_type(16)));
#define VZERO16 {0.f,0.f,0.f,0.f,0.f,0.f,0.f,0.f,0.f,0.f,0.f,0.f,0.f,0.f,0.f,0.f}

// ---- ws layout (float offsets, all multiples of 16) ----
#define OQ     0        // Q[1024]
#define OS     1024     // S[16]
#define OZ     1040     // z[2048]
#define OH     3088     // hbuf[1024]
#define OY     4112     // ybuf[1024]
#define OP     5136     // P[16][1024] normalized pooled nodes
#define OSUMP  21520    // sum partials 3125*16
#define OQK    71520    // qk[1024][16]
#define OSC    87904    // exp-weights [C][16]
#define OPP    887904   // pool partials nb*16384

__device__ __forceinline__ int brev4(int l){
  return ((l&1)<<3)|((l&2)<<1)|((l&4)>>1)|((l&8)>>3);
}

// Sum 16 values (in an f32x16) over all 64 lanes.
// Lanes l<16 end up holding the total for head brev4(l).
__device__ __forceinline__ float vred16(f32x16 v, int lane){
  float send, got;
#define RS(A,B,M) \
  send = (lane&M)? v[A] : v[B]; \
  got  = __shfl_xor(send, M);   \
  v[A] = ((lane&M)? v[B] : v[A]) + got;
  RS(0,8,1) RS(1,9,1) RS(2,10,1) RS(3,11,1)
  RS(4,12,1) RS(5,13,1) RS(6,14,1) RS(7,15,1)
  RS(0,4,2) RS(1,5,2) RS(2,6,2) RS(3,7,2)
  RS(0,2,4) RS(1,3,4)
  RS(0,1,8)
#undef RS
  float t = v[0];
  t += __shfl_xor(t,16);
  t += __shfl_xor(t,32);
  return t;
}

// ---- one-shot 16-output matvec block: out_j = sum_i x[i]*W[i*1024+j] ----
// block=256, grid=64 (16 outputs per block). Returns s valid for tid<16.
template<int IN>
__device__ __forceinline__ float mv_dot(const float* __restrict__ W,
    const float* __restrict__ x, int tid, int jblk){
  __shared__ float xs[IN];
  __shared__ float red[16][17];
  for (int k=tid;k<IN;k+=256) xs[k]=x[k];
  __syncthreads();
  int jq = tid&15, iq = tid>>4;
  int j = jblk*16 + jq;
  float acc = 0.f;
#pragma unroll 8
  for (int i=iq;i<IN;i+=16)
    acc = fmaf(xs[i], W[(size_t)i*1024 + j], acc);
  red[iq][jq] = acc;
  __syncthreads();
  float s = 0.f;
  if (tid < 16){
#pragma unroll
    for (int ii=0;ii<16;ii++) s += red[ii][tid];
  }
  return s;
}

// Q = z_prev@Wq + bq; also copy z_prev into z[1024:2048]
__global__ __launch_bounds__(256) void hm_mvQ(const float* __restrict__ W,
    const float* __restrict__ x, const float* __restrict__ bq,
    float* __restrict__ Q, float* __restrict__ z){
  float s = mv_dot<1024>(W, x, threadIdx.x, blockIdx.x);
  int tid = threadIdx.x;
  int j0 = blockIdx.x*16;
  if (tid < 16){
    Q[j0+tid] = s + bq[j0+tid];
    z[1024 + j0 + tid] = x[j0 + tid];
  }
}

// qk[i][h] = sum_t Wk[i][h*64+t] * Q[h*64+t]; one wave per row i.
__global__ __launch_bounds__(256) void hm_qk2(const float* __restrict__ Wk,
    const float* __restrict__ Q, float* __restrict__ qk){
  __shared__ float qlds[1024];
  int tid = threadIdx.x;
  for (int k=tid;k<1024;k+=256) qlds[k]=Q[k];
  __syncthreads();
  int w = tid>>6, l = tid&63;
  int i = blockIdx.x*4 + w;
  const float* wr = Wk + (size_t)i*1024 + l;
  f32x16 acc = VZERO16;
#define QKS(k) acc[k] = wr[k*64] * qlds[k*64 + l];
  QKS(0) QKS(1) QKS(2) QKS(3) QKS(4) QKS(5) QKS(6) QKS(7)
  QKS(8) QKS(9) QKS(10) QKS(11) QKS(12) QKS(13) QKS(14) QKS(15)
#undef QKS
  float t = vred16(acc, l);
  if (l < 16) qk[i*16 + brev4(l)] = t;
}

// weights[c][h] = exp( (nodes[c]·qk[:,h]) / 8 )   (softmax shift-invariance:
// no max subtraction needed — |score| <= |n||qk|/8, far from overflow; the
// per-head K-bias term Q·bk is constant over c and cancels too)
// Also emits per-cb partial sums sump[cb*16+h].
__global__ __launch_bounds__(256) void hm_scores2(const float* __restrict__ nodes,
    const float* __restrict__ qk, float* __restrict__ sc,
    float* __restrict__ sump){
  __shared__ float part[16][4][16];
  __shared__ float esum[16][17];
  const int tid = threadIdx.x, w = tid>>6, l = tid&63;
  const f32x16* qv = (const f32x16*)qk;
  const int i0 = w*256 + l*4;          // this lane's 4 dims (float4-aligned)
  f32x16 q0 = qv[i0+0];
  f32x16 q1 = qv[i0+1];
  f32x16 q2 = qv[i0+2];
  f32x16 q3 = qv[i0+3];
  const float4* n4 = (const float4*)nodes;

  for (int cb = blockIdx.x; cb < 3125; cb += gridDim.x){
    size_t base = (size_t)cb*16*256 + w*64 + l;
    float4 cur = n4[base];
#pragma unroll 4
    for (int r=0;r<16;r++){
      float4 nv = cur;
      if (r < 15) cur = n4[base + (size_t)(r+1)*256];
      f32x16 acc = q0*nv.x + q1*nv.y + q2*nv.z + q3*nv.w;
      float t = vred16(acc, l);
      if (l < 16) part[r][w][brev4(l)] = t;
    }
    __syncthreads();
    {
      int r = tid>>4, h = tid&15;
      float s = part[r][0][h]+part[r][1][h]+part[r][2][h]+part[r][3][h];
      float e = __expf(s * 0.125f);
      sc[((size_t)cb*16 + r)*16 + h] = e;
      esum[r][h] = e;
    }
    __syncthreads();
    if (tid < 16){
      float s2 = 0.f;
#pragma unroll
      for (int rr=0;rr<16;rr++) s2 += esum[rr][tid];
      sump[cb*16 + tid] = s2;
    }
    __syncthreads();
  }
}

__global__ __launch_bounds__(256) void hm_sumfin(const float* __restrict__ sump,
    float* __restrict__ S){
  __shared__ float red[16][17];
  int t = threadIdx.x, h = t&15, g = t>>4;
  float s = 0.f;
  for (int b=g; b<3125; b+=16) s += sump[b*16 + h];
  red[g][h] = s;
  __syncthreads();
  if (t < 16){
    float v = 0.f;
#pragma unroll
    for (int gg=0; gg<16; gg++) v += red[gg][t];
    S[t] = v;
  }
}

// Pool partials: acc[j][h] += nodes[c][dim0+j] * weights[c][h], no reduce.
__global__ __launch_bounds__(256) void hm_pool2(const float* __restrict__ nodes,
    const float* __restrict__ sc, float* __restrict__ parts){
  const int tid = threadIdx.x, w = tid>>6, l = tid&63;
  f32x16 a0 = VZERO16, a1 = VZERO16, a2 = VZERO16, a3 = VZERO16;
  const float4*  n4  = (const float4*)nodes;
  const f32x16*  u16 = (const f32x16*)sc;
  const int stride = gridDim.x;
  int c = blockIdx.x;
  float4 nv_n; f32x16 u_n;
  if (c < C_N){
    nv_n = n4[(size_t)c*256 + w*64 + l];
    u_n  = u16[c];
  }
  while (c < C_N){
    float4 nv = nv_n;
    f32x16 u = u_n;
    int cn = c + stride;
    if (cn < C_N){
      nv_n = n4[(size_t)cn*256 + w*64 + l];
      u_n  = u16[cn];
    }
    a0 += u * nv.x;
    a1 += u * nv.y;
    a2 += u * nv.z;
    a3 += u * nv.w;
    c = cn;
  }
  float* p = parts + (size_t)blockIdx.x*16384 + w*256 + l*4;
#pragma unroll
  for (int h=0;h<16;h++){
    float4 o = make_float4(a0[h],a1[h],a2[h],a3[h]);
    *(float4*)(p + h*1024) = o;
  }
}

// P[h*1024+i] = sum_b parts / S[h]
__global__ __launch_bounds__(256) void hm_pool_red2(const float* __restrict__ parts,
    const float* __restrict__ S, float* __restrict__ P, int nb){
  int j = blockIdx.x*256 + threadIdx.x;
  float s = 0.f;
  for (int b=0;b<nb;b++) s += parts[(size_t)b*16384 + j];
  P[j] = s / S[j>>10];
}

// z[j] = P[h]·Wv[:,j] + bv[j], h = j>>6 (constant per 16-output block)
__global__ __launch_bounds__(256) void hm_mvV(const float* __restrict__ W,
    const float* __restrict__ P, const float* __restrict__ bv,
    float* __restrict__ z){
  const float* x = P + (size_t)(blockIdx.x>>2)*1024;
  float s = mv_dot<1024>(W, x, threadIdx.x, blockIdx.x);
  int tid = threadIdx.x;
  if (tid < 16){
    int j = blockIdx.x*16 + tid;
    z[j] = s + bv[j];
  }
}

__global__ __launch_bounds__(256) void hm_mvW1(const float* __restrict__ W,
    const float* __restrict__ z, const float* __restrict__ b1,
    float* __restrict__ hbuf){
  float s = mv_dot<2048>(W, z, threadIdx.x, blockIdx.x);
  int tid = threadIdx.x;
  if (tid < 16){
    int j = blockIdx.x*16 + tid;
    float v = s + b1[j];
    hbuf[j] = 0.5f * v * (1.0f + erff(v * 0.70710678118654752f));
  }
}

__global__ __launch_bounds__(256) void hm_mvW2(const float* __restrict__ W,
    const float* __restrict__ hb, const float* __restrict__ b2,
    float* __restrict__ y){
  float s = mv_dot<1024>(W, hb, threadIdx.x, blockIdx.x);
  int tid = threadIdx.x;
  if (tid < 16){
    int j = blockIdx.x*16 + tid;
    y[j] = s + b2[j];
  }
}

__global__ __launch_bounds__(256) void hm_rms(const float* __restrict__ y,
    const float* __restrict__ scale, float* __restrict__ out){
  __shared__ float red[4];
  __shared__ float msv;
  int tid = threadIdx.x;
  float local = 0.f;
  for (int j=tid;j<1024;j+=256){ float t = y[j]; local = fmaf(t,t,local); }
#pragma unroll
  for (int m=1;m<64;m<<=1) local += __shfl_xor(local, m);
  if ((tid&63)==0) red[tid>>6] = local;
  __syncthreads();
  if (tid==0){
    float s = red[0]+red[1]+red[2]+red[3];
    msv = rsqrtf(s*(1.0f/1024.0f) + 1e-6f);
  }
  __syncthreads();
  float r = msv;
  for (int j=tid;j<1024;j+=256) out[j] = scale[j]*y[j]*r;
}

extern "C" void kernel_launch(void* const* d_in, const int* in_sizes, int n_in,
                              void* d_out, int out_size, void* d_ws, size_t ws_size,
                              hipStream_t stream){
  const float* nodes  = (const float*)d_in[0];
  const float* z_prev = (const float*)d_in[1];
  const float* Wq = (const float*)d_in[2];
  const float* bq = (const float*)d_in[3];
  const float* Wk = (const float*)d_in[4];
  // d_in[5] = bk — cancels in softmax, unused
  const float* Wv = (const float*)d_in[6];
  const float* bv = (const float*)d_in[7];
  const float* W1 = (const float*)d_in[8];
  const float* b1 = (const float*)d_in[9];
  const float* W2 = (const float*)d_in[10];
  const float* b2 = (const float*)d_in[11];
  const float* scale = (const float*)d_in[12];
  float* ws  = (float*)d_ws;
  float* out = (float*)d_out;

  float* Qv   = ws + OQ;
  float* Sv   = ws + OS;
  float* z    = ws + OZ;
  float* hbuf = ws + OH;
  float* ybuf = ws + OY;
  float* P    = ws + OP;
  float* sump = ws + OSUMP;
  float* qk   = ws + OQK;
  float* sc   = ws + OSC;
  float* pp   = ws + OPP;

  size_t wsf = ws_size/4;
  int nbp = 1;
  if (wsf > (size_t)(OPP + 16384)) nbp = (int)((wsf - OPP)/16384);
  if (nbp > 512) nbp = 512;
  if (nbp < 1) nbp = 1;

  hm_mvQ    <<<64,  256, 0, stream>>>(Wq, z_prev, bq, Qv, z);
  hm_qk2    <<<256, 256, 0, stream>>>(Wk, Qv, qk);
  hm_scores2<<<1563,256, 0, stream>>>(nodes, qk, sc, sump);
  hm_sumfin <<<1,   256, 0, stream>>>(sump, Sv);
  hm_pool2  <<<nbp, 256, 0, stream>>>(nodes, sc, pp);
  hm_pool_red2<<<64,256, 0, stream>>>(pp, Sv, P, nbp);
  hm_mvV    <<<64,  256, 0, stream>>>(Wv, P, bv, z);
  hm_mvW1   <<<64,  256, 0, stream>>>(W1, z, b1, hbuf);
  hm_mvW2   <<<64,  256, 0, stream>>>(W2, hbuf, b2, ybuf);
  hm_rms    <<<1,   256, 0, stream>>>(ybuf, scale, out);
}

// Round 3
// 151.796 us; speedup vs baseline: 2.6392x; 2.1118x over previous
//
#include <hip/hip_runtime.h>
#include <math.h>

#define C_N 50000

typedef float f32x16 __attribute__((ext_vector_type(16)));
#define VZERO16 {0.f,0.f,0.f,0.f,0.f,0.f,0.f,0.f,0.f,0.f,0.f,0.f,0.f,0.f,0.f,0.f}

// ---- ws layout (float offsets, all multiples of 16) ----
#define OQ     0        // Q[1024]
#define OS     1024     // S[16]
#define OZ     1040     // z[2048]
#define OH     3088     // hbuf[1024]
#define OY     4112     // ybuf[1024]
#define OP     5136     // P[16][1024] normalized pooled nodes
#define OSUMB  21520    // per-block head sums 512*16
#define OQK    29712    // qk[1024][16]
#define OPP2   46096    // 2nd-level pool partials 32*16384
#define OPP    570384   // pool partials nb*16384

__device__ __forceinline__ int brev4(int l){
  return ((l&1)<<3)|((l&2)<<1)|((l&4)>>1)|((l&8)>>3);
}

// Sum 16 values (in an f32x16) over all 64 lanes.
// Lanes l<16 end up holding the total for head brev4(l).
__device__ __forceinline__ float vred16(f32x16 v, int lane){
  float send, got;
#define RS(A,B,M) \
  send = (lane&M)? v[A] : v[B]; \
  got  = __shfl_xor(send, M);   \
  v[A] = ((lane&M)? v[B] : v[A]) + got;
  RS(0,8,1) RS(1,9,1) RS(2,10,1) RS(3,11,1)
  RS(4,12,1) RS(5,13,1) RS(6,14,1) RS(7,15,1)
  RS(0,4,2) RS(1,5,2) RS(2,6,2) RS(3,7,2)
  RS(0,2,4) RS(1,3,4)
  RS(0,1,8)
#undef RS
  float t = v[0];
  t += __shfl_xor(t,16);
  t += __shfl_xor(t,32);
  return t;
}

// ---- one-shot 16-output matvec block: out_j = sum_i x[i]*W[i*1024+j] ----
template<int IN>
__device__ __forceinline__ float mv_dot(const float* __restrict__ W,
    const float* __restrict__ x, int tid, int jblk){
  __shared__ float xs[IN];
  __shared__ float red[16][17];
  for (int k=tid;k<IN;k+=256) xs[k]=x[k];
  __syncthreads();
  int jq = tid&15, iq = tid>>4;
  int j = jblk*16 + jq;
  float acc = 0.f;
#pragma unroll 8
  for (int i=iq;i<IN;i+=16)
    acc = fmaf(xs[i], W[(size_t)i*1024 + j], acc);
  red[iq][jq] = acc;
  __syncthreads();
  float s = 0.f;
  if (tid < 16){
#pragma unroll
    for (int ii=0;ii<16;ii++) s += red[ii][tid];
  }
  return s;
}

// Q = z_prev@Wq + bq; also copy z_prev into z[1024:2048]
__global__ __launch_bounds__(256) void hm_mvQ(const float* __restrict__ W,
    const float* __restrict__ x, const float* __restrict__ bq,
    float* __restrict__ Q, float* __restrict__ z){
  float s = mv_dot<1024>(W, x, threadIdx.x, blockIdx.x);
  int tid = threadIdx.x;
  int j0 = blockIdx.x*16;
  if (tid < 16){
    Q[j0+tid] = s + bq[j0+tid];
    z[1024 + j0 + tid] = x[j0 + tid];
  }
}

// qk[i][h] = sum_t Wk[i][h*64+t] * Q[h*64+t]; one wave per row i.
__global__ __launch_bounds__(256) void hm_qk2(const float* __restrict__ Wk,
    const float* __restrict__ Q, float* __restrict__ qk){
  __shared__ float qlds[1024];
  int tid = threadIdx.x;
  for (int k=tid;k<1024;k+=256) qlds[k]=Q[k];
  __syncthreads();
  int w = tid>>6, l = tid&63;
  int i = blockIdx.x*4 + w;
  const float* wr = Wk + (size_t)i*1024 + l;
  f32x16 acc = VZERO16;
#define QKS(k) acc[k] = wr[k*64] * qlds[k*64 + l];
  QKS(0) QKS(1) QKS(2) QKS(3) QKS(4) QKS(5) QKS(6) QKS(7)
  QKS(8) QKS(9) QKS(10) QKS(11) QKS(12) QKS(13) QKS(14) QKS(15)
#undef QKS
  float t = vred16(acc, l);
  if (l < 16) qk[i*16 + brev4(l)] = t;
}

// Fused scores+softmax-exp+pool. Per 16-row batch:
//   phase1: score s[c][h] = nodes[c]·qk[:,h]  (cross-wave reduce in LDS)
//   phase2: e = exp(s/8) into LDS (no max shift: |s|<~3, safe; Q·bk bias
//           is constant per head and cancels in softmax)
//   phase3: pool accs a[j][h] += nodes[c][j]*e[c][h] (rows re-read, L1/L2-hot)
// Emits per-block pool partials and per-block head sums (for S).
__global__ __launch_bounds__(256) void hm_fused(const float* __restrict__ nodes,
    const float* __restrict__ qk, float* __restrict__ parts,
    float* __restrict__ sumpb){
  __shared__ float part[16][4][16];
  __shared__ float eb[16][16];
  const int tid = threadIdx.x, w = tid>>6, l = tid&63;
  const f32x16* qv = (const f32x16*)qk;
  const int i0 = w*256 + l*4;
  f32x16 q0 = qv[i0+0];
  f32x16 q1 = qv[i0+1];
  f32x16 q2 = qv[i0+2];
  f32x16 q3 = qv[i0+3];
  f32x16 a0 = VZERO16, a1 = VZERO16, a2 = VZERO16, a3 = VZERO16;
  float ssum = 0.f;
  const float4* n4 = (const float4*)nodes;
  const int r_ = tid>>4, h_ = tid&15;

  for (int cb = blockIdx.x; cb < 3125; cb += gridDim.x){
    size_t base = (size_t)cb*4096 + w*64 + l;
    float4 cur = n4[base];
#pragma unroll 4
    for (int r=0;r<16;r++){
      float4 nv = cur;
      if (r < 15) cur = n4[base + (size_t)(r+1)*256];
      f32x16 acc = q0*nv.x + q1*nv.y + q2*nv.z + q3*nv.w;
      float t = vred16(acc, l);
      if (l < 16) part[r][w][brev4(l)] = t;
    }
    __syncthreads();
    {
      float s = part[r_][0][h_]+part[r_][1][h_]+part[r_][2][h_]+part[r_][3][h_];
      eb[r_][h_] = __expf(s * 0.125f);
    }
    __syncthreads();
    if (tid < 16){
#pragma unroll
      for (int rr=0;rr<16;rr++) ssum += eb[rr][tid];
    }
#pragma unroll 4
    for (int r=0;r<16;r++){
      float4 nv = n4[base + (size_t)r*256];     // L1/L2 hit (just read)
      f32x16 u = *(const f32x16*)&eb[r][0];     // LDS broadcast
      a0 += u*nv.x; a1 += u*nv.y; a2 += u*nv.z; a3 += u*nv.w;
    }
    __syncthreads();
  }
  float* p = parts + (size_t)blockIdx.x*16384 + w*256 + l*4;
#pragma unroll
  for (int h=0;h<16;h++){
    float4 o = make_float4(a0[h],a1[h],a2[h],a3[h]);
    *(float4*)(p + h*1024) = o;
  }
  if (tid < 16) sumpb[blockIdx.x*16 + tid] = ssum;
}

// S[h] = sum over blocks of sumpb
__global__ __launch_bounds__(256) void hm_sumfin(const float* __restrict__ sumpb,
    float* __restrict__ S, int nb){
  __shared__ float red[16][17];
  int t = threadIdx.x, h = t&15, g = t>>4;
  float s = 0.f;
  for (int b=g; b<nb; b+=16) s += sumpb[b*16 + h];
  red[g][h] = s;
  __syncthreads();
  if (t < 16){
    float v = 0.f;
#pragma unroll
    for (int gg=0; gg<16; gg++) v += red[gg][t];
    S[t] = v;
  }
}

// Stage A: pp2[y][j] = sum of 16 partials
__global__ __launch_bounds__(256) void hm_predA(const float* __restrict__ parts,
    float* __restrict__ pp2, int nb){
  int j = blockIdx.x*256 + threadIdx.x;
  int b0 = blockIdx.y*16;
  int b1 = b0+16 < nb ? b0+16 : nb;
  float s = 0.f;
  for (int b=b0;b<b1;b++) s += parts[(size_t)b*16384 + j];
  pp2[(size_t)blockIdx.y*16384 + j] = s;
}

// Stage B: P[j] = (sum_y pp2[y][j]) / S[j>>10]
__global__ __launch_bounds__(256) void hm_predB(const float* __restrict__ pp2,
    const float* __restrict__ S, float* __restrict__ P, int ny){
  int j = blockIdx.x*256 + threadIdx.x;
  float s = 0.f;
  for (int y=0;y<ny;y++) s += pp2[(size_t)y*16384 + j];
  P[j] = s / S[j>>10];
}

// z[j] = P[h]·Wv[:,j] + bv[j], h = j>>6
__global__ __launch_bounds__(256) void hm_mvV(const float* __restrict__ W,
    const float* __restrict__ P, const float* __restrict__ bv,
    float* __restrict__ z){
  const float* x = P + (size_t)(blockIdx.x>>2)*1024;
  float s = mv_dot<1024>(W, x, threadIdx.x, blockIdx.x);
  int tid = threadIdx.x;
  if (tid < 16){
    int j = blockIdx.x*16 + tid;
    z[j] = s + bv[j];
  }
}

__global__ __launch_bounds__(256) void hm_mvW1(const float* __restrict__ W,
    const float* __restrict__ z, const float* __restrict__ b1,
    float* __restrict__ hbuf){
  float s = mv_dot<2048>(W, z, threadIdx.x, blockIdx.x);
  int tid = threadIdx.x;
  if (tid < 16){
    int j = blockIdx.x*16 + tid;
    float v = s + b1[j];
    hbuf[j] = 0.5f * v * (1.0f + erff(v * 0.70710678118654752f));
  }
}

__global__ __launch_bounds__(256) void hm_mvW2(const float* __restrict__ W,
    const float* __restrict__ hb, const float* __restrict__ b2,
    float* __restrict__ y){
  float s = mv_dot<1024>(W, hb, threadIdx.x, blockIdx.x);
  int tid = threadIdx.x;
  if (tid < 16){
    int j = blockIdx.x*16 + tid;
    y[j] = s + b2[j];
  }
}

__global__ __launch_bounds__(256) void hm_rms(const float* __restrict__ y,
    const float* __restrict__ scale, float* __restrict__ out){
  __shared__ float red[4];
  __shared__ float msv;
  int tid = threadIdx.x;
  float local = 0.f;
  for (int j=tid;j<1024;j+=256){ float t = y[j]; local = fmaf(t,t,local); }
#pragma unroll
  for (int m=1;m<64;m<<=1) local += __shfl_xor(local, m);
  if ((tid&63)==0) red[tid>>6] = local;
  __syncthreads();
  if (tid==0){
    float s = red[0]+red[1]+red[2]+red[3];
    msv = rsqrtf(s*(1.0f/1024.0f) + 1e-6f);
  }
  __syncthreads();
  float r = msv;
  for (int j=tid;j<1024;j+=256) out[j] = scale[j]*y[j]*r;
}

extern "C" void kernel_launch(void* const* d_in, const int* in_sizes, int n_in,
                              void* d_out, int out_size, void* d_ws, size_t ws_size,
                              hipStream_t stream){
  const float* nodes  = (const float*)d_in[0];
  const float* z_prev = (const float*)d_in[1];
  const float* Wq = (const float*)d_in[2];
  const float* bq = (const float*)d_in[3];
  const float* Wk = (const float*)d_in[4];
  // d_in[5] = bk — cancels in softmax, unused
  const float* Wv = (const float*)d_in[6];
  const float* bv = (const float*)d_in[7];
  const float* W1 = (const float*)d_in[8];
  const float* b1 = (const float*)d_in[9];
  const float* W2 = (const float*)d_in[10];
  const float* b2 = (const float*)d_in[11];
  const float* scale = (const float*)d_in[12];
  float* ws  = (float*)d_ws;
  float* out = (float*)d_out;

  float* Qv   = ws + OQ;
  float* Sv   = ws + OS;
  float* z    = ws + OZ;
  float* hbuf = ws + OH;
  float* ybuf = ws + OY;
  float* P    = ws + OP;
  float* sumb = ws + OSUMB;
  float* qk   = ws + OQK;
  float* pp2  = ws + OPP2;
  float* pp   = ws + OPP;

  size_t wsf = ws_size/4;
  int nbp = 1;
  if (wsf > (size_t)(OPP + 16384)) nbp = (int)((wsf - OPP)/16384);
  if (nbp > 512) nbp = 512;
  if (nbp < 1) nbp = 1;
  int ny = (nbp + 15)/16;   // <= 32

  hm_mvQ   <<<64,  256, 0, stream>>>(Wq, z_prev, bq, Qv, z);
  hm_qk2   <<<256, 256, 0, stream>>>(Wk, Qv, qk);
  hm_fused <<<nbp, 256, 0, stream>>>(nodes, qk, pp, sumb);
  hm_sumfin<<<1,   256, 0, stream>>>(sumb, Sv, nbp);
  hm_predA <<<dim3(64,ny), 256, 0, stream>>>(pp, pp2, nbp);
  hm_predB <<<64,  256, 0, stream>>>(pp2, Sv, P, ny);
  hm_mvV   <<<64,  256, 0, stream>>>(Wv, P, bv, z);
  hm_mvW1  <<<64,  256, 0, stream>>>(W1, z, b1, hbuf);
  hm_mvW2  <<<64,  256, 0, stream>>>(W2, hbuf, b2, ybuf);
  hm_rms   <<<1,   256, 0, stream>>>(ybuf, scale, out);
}